// Round 1
// baseline (350.124 us; speedup 1.0000x reference)
//
#include <hip/hip_runtime.h>

// Problem constants (B, N, C, H from reference)
#define B_SZ 4
#define SEQ  2048
#define CH   768
#define NH   12
#define HD   64

typedef float f32x4 __attribute__((ext_vector_type(4)));
typedef __bf16 bf16x8 __attribute__((ext_vector_type(8)));

#define MFMA(a, b, c) __builtin_amdgcn_mfma_f32_16x16x32_bf16(a, b, c, 0, 0, 0)

__device__ __forceinline__ unsigned short f2bf(float f) {
    union { float f; unsigned int u; } cv; cv.f = f;
    unsigned int u = cv.u;
    unsigned int r = (u + 0x7fffu + ((u >> 16) & 1u)) >> 16;
    return (unsigned short)r;
}

// ---------------- fp32 -> bf16 convert ----------------
__global__ __launch_bounds__(256) void convert_bf16(const float* __restrict__ src,
                                                    unsigned short* __restrict__ dst, int n) {
    int i = (blockIdx.x * 256 + threadIdx.x) * 4;
    if (i >= n) return;
    float4 v = *(const float4*)(src + i);
    ushort4 o;
    o.x = f2bf(v.x); o.y = f2bf(v.y); o.z = f2bf(v.z); o.w = f2bf(v.w);
    *(ushort4*)(dst + i) = o;
}

// ---------------- shared 64x64 (BK=64) MFMA mainloop: C = A(MxK) * B(NxK)^T ----------------
__device__ __forceinline__ void gemm64_mainloop(const unsigned short* __restrict__ A,
                                                const unsigned short* __restrict__ Bm,
                                                int K, int rowBlk, int colBlk,
                                                unsigned short (*As)[72], unsigned short (*Bs)[72],
                                                f32x4 acc[2][2]) {
    const int tid  = threadIdx.x;
    const int lane = tid & 63;
    const int wid  = tid >> 6;
    const int quad = lane >> 4, l16 = lane & 15;
    const int wm = wid >> 1, wn = wid & 1;

    f32x4 z = {0.f, 0.f, 0.f, 0.f};
    acc[0][0] = z; acc[0][1] = z; acc[1][0] = z; acc[1][1] = z;

    for (int k0 = 0; k0 < K; k0 += 64) {
#pragma unroll
        for (int i = 0; i < 2; ++i) {
            int c = tid + i * 256;
            int r = c >> 3, co = (c & 7) * 8;   // 64 rows x 8 chunks of 8 bf16
            *(uint4*)(&As[r][co]) = *(const uint4*)(A + (size_t)(rowBlk + r) * K + k0 + co);
            *(uint4*)(&Bs[r][co]) = *(const uint4*)(Bm + (size_t)(colBlk + r) * K + k0 + co);
        }
        __syncthreads();
#pragma unroll
        for (int kc = 0; kc < 2; ++kc) {
            bf16x8 a0 = *(const bf16x8*)(&As[wm * 32 + l16][kc * 32 + quad * 8]);
            bf16x8 a1 = *(const bf16x8*)(&As[wm * 32 + 16 + l16][kc * 32 + quad * 8]);
            bf16x8 b0 = *(const bf16x8*)(&Bs[wn * 32 + l16][kc * 32 + quad * 8]);
            bf16x8 b1 = *(const bf16x8*)(&Bs[wn * 32 + 16 + l16][kc * 32 + quad * 8]);
            acc[0][0] = MFMA(a0, b0, acc[0][0]);
            acc[0][1] = MFMA(a0, b1, acc[0][1]);
            acc[1][0] = MFMA(a1, b0, acc[1][0]);
            acc[1][1] = MFMA(a1, b1, acc[1][1]);
        }
        __syncthreads();
    }
}

// ---------------- QKV GEMM: X(8192x768) @ Wqkv(2304x768)^T, scatter to Q/K/Vt ----------------
__global__ __launch_bounds__(256) void qkv_gemm(const unsigned short* __restrict__ Xb,
                                                const unsigned short* __restrict__ Wb,
                                                unsigned short* __restrict__ Qb,
                                                unsigned short* __restrict__ Kb,
                                                unsigned short* __restrict__ Vt) {
    __shared__ unsigned short As[64][72], Bs[64][72];
    f32x4 acc[2][2];
    const int rowBlk = blockIdx.x * 64, colBlk = blockIdx.y * 64;
    gemm64_mainloop(Xb, Wb, CH, rowBlk, colBlk, As, Bs, acc);

    const int lane = threadIdx.x & 63, wid = threadIdx.x >> 6;
    const int quad = lane >> 4, l16 = lane & 15, wm = wid >> 1, wn = wid & 1;
#pragma unroll
    for (int mb = 0; mb < 2; ++mb)
#pragma unroll
        for (int nb = 0; nb < 2; ++nb)
#pragma unroll
            for (int r = 0; r < 4; ++r) {
                int row = rowBlk + wm * 32 + mb * 16 + quad * 4 + r;   // 0..8191
                int col = colBlk + wn * 32 + nb * 16 + l16;            // 0..2303
                float v = acc[mb][nb][r];
                int b = row >> 11, n = row & (SEQ - 1);
                int which = (col >= 2 * CH) ? 2 : ((col >= CH) ? 1 : 0);
                int cc = col - which * CH;
                int h = cc >> 6, d = cc & 63;
                int bh = b * NH + h;
                if (which == 0)      Qb[(size_t)(bh * SEQ + n) * HD + d] = f2bf(v * 0.125f);
                else if (which == 1) Kb[(size_t)(bh * SEQ + n) * HD + d] = f2bf(v);
                else                 Vt[(size_t)(bh * HD + d) * SEQ + n] = f2bf(v);
            }
}

// ---------------- Flash attention: one block per (b, h, 64-query tile) ----------------
__global__ __launch_bounds__(256) void flash_attn(const unsigned short* __restrict__ Qb,
                                                  const unsigned short* __restrict__ Kb,
                                                  const unsigned short* __restrict__ Vt,
                                                  unsigned short* __restrict__ Ab) {
    __shared__ unsigned short Ks[64][72];       // [key_local][d]
    __shared__ unsigned short Vs[64][72];       // [d][key_local]
    __shared__ unsigned short Pb[4][16][72];    // per-wave P tile [query][key_local]

    const int tid  = threadIdx.x;
    const int lane = tid & 63, wid = tid >> 6;
    const int quad = lane >> 4, l16 = lane & 15;

    const int qblk = blockIdx.x;       // 0..31
    const int h    = blockIdx.y;       // 0..11
    const int b    = blockIdx.z;       // 0..3
    const int bh   = b * NH + h;

    // Q fragments for this wave's 16 queries (held whole kernel)
    const int qrow = qblk * 64 + wid * 16 + l16;
    bf16x8 aq[2];
#pragma unroll
    for (int kc = 0; kc < 2; ++kc)
        aq[kc] = *(const bf16x8*)(Qb + (size_t)(bh * SEQ + qrow) * HD + kc * 32 + quad * 8);

    float m_run[4], l_run[4];
    f32x4 Oacc[4];
    f32x4 z = {0.f, 0.f, 0.f, 0.f};
#pragma unroll
    for (int r = 0; r < 4; ++r) { m_run[r] = -1e30f; l_run[r] = 0.f; }
#pragma unroll
    for (int nd = 0; nd < 4; ++nd) Oacc[nd] = z;

    for (int kb = 0; kb < SEQ / 64; ++kb) {
        const int kbase = kb * 64;
        __syncthreads();   // prior-iteration consumers done
#pragma unroll
        for (int i = 0; i < 2; ++i) {
            int c = tid + i * 256;
            int r = c >> 3, co = (c & 7) * 8;
            *(uint4*)(&Ks[r][co]) = *(const uint4*)(Kb + (size_t)(bh * SEQ + kbase + r) * HD + co);
            *(uint4*)(&Vs[r][co]) = *(const uint4*)(Vt + (size_t)(bh * HD + r) * SEQ + kbase + co);
        }
        __syncthreads();

        // S = Q K^T  (16 queries x 64 keys per wave)
        f32x4 s[4];
#pragma unroll
        for (int nb = 0; nb < 4; ++nb) {
            s[nb] = z;
#pragma unroll
            for (int kc = 0; kc < 2; ++kc) {
                bf16x8 bk = *(const bf16x8*)(&Ks[nb * 16 + l16][kc * 32 + quad * 8]);
                s[nb] = MFMA(aq[kc], bk, s[nb]);
            }
        }

        // online softmax in registers; row = quad*4 + r owned by this quad's 16 lanes
        float mnew[4], alpha[4], rs[4];
#pragma unroll
        for (int r = 0; r < 4; ++r) {
            float mb_ = fmaxf(fmaxf(s[0][r], s[1][r]), fmaxf(s[2][r], s[3][r]));
#pragma unroll
            for (int off = 1; off < 16; off <<= 1)
                mb_ = fmaxf(mb_, __shfl_xor(mb_, off, 16));
            mnew[r]  = fmaxf(m_run[r], mb_);
            alpha[r] = __expf(m_run[r] - mnew[r]);
            m_run[r] = mnew[r];
            rs[r] = 0.f;
        }
#pragma unroll
        for (int nb = 0; nb < 4; ++nb)
#pragma unroll
            for (int r = 0; r < 4; ++r) {
                float p = __expf(s[nb][r] - mnew[r]);
                s[nb][r] = p;
                rs[r] += p;
            }
#pragma unroll
        for (int r = 0; r < 4; ++r) {
#pragma unroll
            for (int off = 1; off < 16; off <<= 1)
                rs[r] += __shfl_xor(rs[r], off, 16);
            l_run[r] = l_run[r] * alpha[r] + rs[r];
        }
#pragma unroll
        for (int nd = 0; nd < 4; ++nd)
#pragma unroll
            for (int r = 0; r < 4; ++r)
                Oacc[nd][r] *= alpha[r];

        // P (C-layout) -> LDS bf16 (for A-layout reload)
#pragma unroll
        for (int nb = 0; nb < 4; ++nb)
#pragma unroll
            for (int r = 0; r < 4; ++r)
                Pb[wid][quad * 4 + r][nb * 16 + l16] = f2bf(s[nb][r]);
        __syncthreads();

        // O += P V
        bf16x8 ap0 = *(const bf16x8*)(&Pb[wid][l16][0 + quad * 8]);
        bf16x8 ap1 = *(const bf16x8*)(&Pb[wid][l16][32 + quad * 8]);
#pragma unroll
        for (int nd = 0; nd < 4; ++nd) {
            bf16x8 bv0 = *(const bf16x8*)(&Vs[nd * 16 + l16][0 + quad * 8]);
            bf16x8 bv1 = *(const bf16x8*)(&Vs[nd * 16 + l16][32 + quad * 8]);
            Oacc[nd] = MFMA(ap0, bv0, Oacc[nd]);
            Oacc[nd] = MFMA(ap1, bv1, Oacc[nd]);
        }
    }

    // write O / l   -> Ab in (b, n, c) layout, bf16
#pragma unroll
    for (int nd = 0; nd < 4; ++nd)
#pragma unroll
        for (int r = 0; r < 4; ++r) {
            int q = qblk * 64 + wid * 16 + quad * 4 + r;
            int d = nd * 16 + l16;
            float v = Oacc[nd][r] / l_run[r];
            Ab[(size_t)(b * SEQ + q) * CH + h * HD + d] = f2bf(v);
        }
}

// ---------------- Projection GEMM: Attn(8192x768) @ proj_w(768x768)^T + bias ----------------
__global__ __launch_bounds__(256) void proj_gemm(const unsigned short* __restrict__ Ab,
                                                 const unsigned short* __restrict__ Pw,
                                                 const float* __restrict__ bias,
                                                 float* __restrict__ out) {
    __shared__ unsigned short As[64][72], Bs[64][72];
    f32x4 acc[2][2];
    const int rowBlk = blockIdx.x * 64, colBlk = blockIdx.y * 64;
    gemm64_mainloop(Ab, Pw, CH, rowBlk, colBlk, As, Bs, acc);

    const int lane = threadIdx.x & 63, wid = threadIdx.x >> 6;
    const int quad = lane >> 4, l16 = lane & 15, wm = wid >> 1, wn = wid & 1;
#pragma unroll
    for (int mb = 0; mb < 2; ++mb)
#pragma unroll
        for (int nb = 0; nb < 2; ++nb)
#pragma unroll
            for (int r = 0; r < 4; ++r) {
                int row = rowBlk + wm * 32 + mb * 16 + quad * 4 + r;
                int col = colBlk + wn * 32 + nb * 16 + l16;
                out[(size_t)row * CH + col] = acc[mb][nb][r] + bias[col];
            }
}

extern "C" void kernel_launch(void* const* d_in, const int* in_sizes, int n_in,
                              void* d_out, int out_size, void* d_ws, size_t ws_size,
                              hipStream_t stream) {
    const float* x      = (const float*)d_in[0];   // (4,2048,768)
    const float* qkv_w  = (const float*)d_in[1];   // (2304,768)
    const float* proj_w = (const float*)d_in[2];   // (768,768)
    const float* proj_b = (const float*)d_in[3];   // (768,)
    float* out = (float*)d_out;

    char* ws = (char*)d_ws;
    const size_t nX  = (size_t)B_SZ * SEQ * CH;        // 6,291,456
    const size_t nW  = (size_t)3 * CH * CH;            // 1,769,472
    const size_t nP  = (size_t)CH * CH;                // 589,824
    const size_t nQ  = (size_t)B_SZ * NH * SEQ * HD;   // 6,291,456

    unsigned short* Xb  = (unsigned short*)(ws);
    unsigned short* Wb  = (unsigned short*)(ws + 2 * nX);
    unsigned short* Pw  = (unsigned short*)(ws + 2 * (nX + nW));
    unsigned short* Qb  = (unsigned short*)(ws + 2 * (nX + nW + nP));
    unsigned short* Kb  = (unsigned short*)(ws + 2 * (nX + nW + nP + nQ));
    unsigned short* Vt  = (unsigned short*)(ws + 2 * (nX + nW + nP + 2 * nQ));
    unsigned short* Ab  = (unsigned short*)(ws + 2 * (nX + nW + nP + 3 * nQ));

    convert_bf16<<<(int)(nX / 1024), 256, 0, stream>>>(x, Xb, (int)nX);
    convert_bf16<<<(int)(nW / 1024), 256, 0, stream>>>(qkv_w, Wb, (int)nW);
    convert_bf16<<<(int)(nP / 1024), 256, 0, stream>>>(proj_w, Pw, (int)nP);

    qkv_gemm<<<dim3((B_SZ * SEQ) / 64, (3 * CH) / 64), 256, 0, stream>>>(Xb, Wb, Qb, Kb, Vt);

    flash_attn<<<dim3(SEQ / 64, NH, B_SZ), 256, 0, stream>>>(Qb, Kb, Vt, Ab);

    proj_gemm<<<dim3((B_SZ * SEQ) / 64, CH / 64), 256, 0, stream>>>(Ab, Pw, proj_b, out);
}